// Round 1
// baseline (135.419 us; speedup 1.0000x reference)
//
#include <hip/hip_runtime.h>
#include <math.h>

// Problem constants (setup_inputs: encodings [8192,64] f32, categorical [8192,25] f32, k=15)
#define Bsz    8192
#define Dd     64
#define NC     25
#define RT     16            // i-rows per block — fully owned, no cross-block traffic
#define WAVES  16            // 1024-thread blocks: 16 waves -> 2 blocks/CU = 32 waves/CU (100% cap)
#define KCAP   16            // >= k+1 (k clamped to 15)
#define EPSf   1e-5f
#define JMASK  2097151u      // enc2 is exactly 2 MB; wrap prefetch offsets (over-prefetch reads stale-but-in-bounds data, unused)

typedef short  short8  __attribute__((ext_vector_type(8)));
typedef float  floatx4 __attribute__((ext_vector_type(4)));

// Fragment-native layout: per 16-row group (4096 B):
//   [hi k0..31 : 1024B][hi k32..63 : 1024B][lo k0..31 : 1024B][lo k32..63 : 1024B]
// within a 1 KB chunk, lane l = quad*16 + c15 owns bytes l*16..l*16+15
// = row (group*16 + c15), elems k = quad*8 + khalf*32 .. +7.
// A wave's operand load = ONE coalesced global_load_dwordx4 (1 KB).

__device__ inline unsigned short f2bf(float x) {           // RNE f32 -> bf16 bits
    unsigned u = __float_as_uint(x);
    u += 0x7FFFu + ((u >> 16) & 1u);
    return (unsigned short)(u >> 16);
}
__device__ inline float bf2f(unsigned short h) { return __uint_as_float(((unsigned)h) << 16); }

// Batcher odd-even mergesort, 16 regs ascending (unsigned). 63 CAS vs bitonic's 80.
// Generated by the canonical iterative recurrence; all loop vars fold at compile time
// (verified construction: yields 5/19/63 comparators for n=4/8/16).
__device__ inline void oesort16(unsigned* a) {
    #pragma unroll
    for (int p = 1; p < 16; p <<= 1) {
        #pragma unroll
        for (int k = p; k >= 1; k >>= 1) {
            #pragma unroll
            for (int j = (k & (p - 1)); j + k < 16; j += 2 * k) {
                #pragma unroll
                for (int i = 0; i < k; ++i) {
                    if (i + j + k < 16 &&
                        ((i + j) / (2 * p)) == ((i + j + k) / (2 * p))) {
                        unsigned x = a[i + j], y = a[i + j + k];
                        a[i + j]     = (x < y) ? x : y;
                        a[i + j + k] = (x < y) ? y : x;
                    }
                }
            }
        }
    }
}
__device__ inline void bclean16(unsigned* t) {   // clean bitonic 16-seq to ascending
    #pragma unroll
    for (int j = 8; j > 0; j >>= 1)
        #pragma unroll
        for (int i = 0; i < 16; ++i) {
            int l = i ^ j;
            if (l > i) {
                unsigned x = t[i], y = t[l];
                t[i] = (x < y) ? x : y;
                t[l] = (x < y) ? y : x;
            }
        }
}
// keep-low-16 merge of two sorted-asc 16-lists: ls = lowest16(ls ∪ b), sorted asc
__device__ inline void bmerge16(unsigned* ls, const unsigned* b) {
    unsigned t[16];
    #pragma unroll
    for (int i = 0; i < 16; ++i) { unsigned x = ls[i], y = b[15 - i]; t[i] = (x < y) ? x : y; }
    bclean16(t);
    #pragma unroll
    for (int i = 0; i < 16; ++i) ls[i] = t[i];
}
__device__ inline void bmerge16_shfl(unsigned* ls, int mask) {   // partner via shfl_xor
    unsigned t[16];
    #pragma unroll
    for (int i = 0; i < 16; ++i) {
        unsigned pv = (unsigned)__shfl_xor((int)ls[15 - i], mask);
        unsigned x = ls[i];
        t[i] = (x < pv) ? x : pv;
    }
    bclean16(t);
    #pragma unroll
    for (int i = 0; i < 16; ++i) ls[i] = t[i];
}

// 12 interleaved MFMAs on a pair of tiles + candidate pack (acc = -2*dot)
// (kept bit-identical to the verified version: d2 assembled post-MFMA in VALU)
__device__ inline void compute_pair(
    short8 ah0, short8 ah1, short8 al0, short8 al1,
    short8 ch0, short8 ch1, short8 cl0, short8 cl1,
    uint4 sva, uint4 svb,
    const short8* bh, const short8* bl, float sqi,
    unsigned* cand, int off)
{
    floatx4 accA = (floatx4){0.f, 0.f, 0.f, 0.f};
    floatx4 accB = (floatx4){0.f, 0.f, 0.f, 0.f};
    accA = __builtin_amdgcn_mfma_f32_16x16x32_bf16(ah0, bh[0], accA, 0, 0, 0);
    accB = __builtin_amdgcn_mfma_f32_16x16x32_bf16(ch0, bh[0], accB, 0, 0, 0);
    accA = __builtin_amdgcn_mfma_f32_16x16x32_bf16(ah0, bl[0], accA, 0, 0, 0);
    accB = __builtin_amdgcn_mfma_f32_16x16x32_bf16(ch0, bl[0], accB, 0, 0, 0);
    accA = __builtin_amdgcn_mfma_f32_16x16x32_bf16(al0, bh[0], accA, 0, 0, 0);
    accB = __builtin_amdgcn_mfma_f32_16x16x32_bf16(cl0, bh[0], accB, 0, 0, 0);
    accA = __builtin_amdgcn_mfma_f32_16x16x32_bf16(ah1, bh[1], accA, 0, 0, 0);
    accB = __builtin_amdgcn_mfma_f32_16x16x32_bf16(ch1, bh[1], accB, 0, 0, 0);
    accA = __builtin_amdgcn_mfma_f32_16x16x32_bf16(ah1, bl[1], accA, 0, 0, 0);
    accB = __builtin_amdgcn_mfma_f32_16x16x32_bf16(ch1, bl[1], accB, 0, 0, 0);
    accA = __builtin_amdgcn_mfma_f32_16x16x32_bf16(al1, bh[1], accA, 0, 0, 0);
    accB = __builtin_amdgcn_mfma_f32_16x16x32_bf16(cl1, bh[1], accB, 0, 0, 0);

    unsigned sa[4] = {sva.x, sva.y, sva.z, sva.w};
    unsigned sb[4] = {svb.x, svb.y, svb.z, svb.w};
    #pragma unroll
    for (int r = 0; r < 4; ++r) {
        float d2a = fmaxf(sqi + __uint_as_float(sa[r] & ~31u) + accA[r], 0.f);
        cand[off + r]     = (__float_as_uint(d2a) & ~31u) | (sa[r] & 31u);
        float d2b = fmaxf(sqi + __uint_as_float(sb[r] & ~31u) + accB[r], 0.f);
        cand[off + 4 + r] = (__float_as_uint(d2b) & ~31u) | (sb[r] & 31u);
    }
}

// Output layout (f32, flat): [0..524287] encodings | [524288..532479] nbr entropy |
// [532480] cluster entropy | [532481] n_populated | [532482..540673] max_groups
//
// Workspace: slab u32[8192] @0 (bits(sq)&~31|label) | enc1 @32768 (2 MB, grouped frags of e)
//   enc2 @2129920 (2 MB, grouped frags of -2e). Prefetch offsets wrap mod 2 MB (JMASK),
//   so no over-read slack is needed beyond enc2's end; slab over-advance reads enc1 (in-bounds, unused).

__global__ __launch_bounds__(256) void pre_kernel(
    const float* __restrict__ enc, const float* __restrict__ cat,
    unsigned int* __restrict__ slab,
    char* __restrict__ enc1, char* __restrict__ enc2,
    float* __restrict__ out_max, float* __restrict__ out_enc)
{
    const int gid = blockIdx.x * 256 + threadIdx.x;   // 1024 x 256 = 262144
    const int p = gid >> 5, pr = gid & 31;            // 32 threads/row, dims 2pr..2pr+1

    // single enc read serves passthrough copy and conversion (coalesced float2)
    float2 ev = ((const float2*)enc)[gid];
    ((float2*)out_enc)[gid] = ev;

    float s = ev.x * ev.x + ev.y * ev.y;
    #pragma unroll
    for (int m = 1; m < 32; m <<= 1) s += __shfl_xor(s, m, 32);   // row ssq

    // fragment-native address for dims d0 = 2pr, 2pr+1 (same 16B piece: d0 even)
    {
        const int g = p >> 4, c15p = p & 15;
        const int d0 = 2 * pr, kh = d0 >> 5, q = (d0 >> 3) & 3, e0 = d0 & 7;
        const int base = g * 4096 + kh * 1024 + (q * 16 + c15p) * 16 + e0 * 2;
        unsigned short ha = f2bf(ev.x), hb = f2bf(ev.y);
        unsigned short la = f2bf(ev.x - bf2f(ha)), lb = f2bf(ev.y - bf2f(hb));
        *(unsigned*)(enc1 + base)        = (unsigned)ha | ((unsigned)hb << 16);
        *(unsigned*)(enc1 + base + 2048) = (unsigned)la | ((unsigned)lb << 16);
        float y0 = -2.f * ev.x, y1 = -2.f * ev.y;
        unsigned short hc = f2bf(y0), hd = f2bf(y1);
        unsigned short lc = f2bf(y0 - bf2f(hc)), ld = f2bf(y1 - bf2f(hd));
        *(unsigned*)(enc2 + base)        = (unsigned)hc | ((unsigned)hd << 16);
        *(unsigned*)(enc2 + base + 2048) = (unsigned)lc | ((unsigned)ld << 16);
    }
    // categorical argmax across 32 lanes (first-max: ties -> min index; cat >= 0 so -1 sentinel safe)
    float cv = (pr < NC) ? cat[p * NC + pr] : -1.f;
    int ci = pr;
    #pragma unroll
    for (int m = 1; m < 32; m <<= 1) {
        float ov = __shfl_xor(cv, m, 32);
        int   oi = __shfl_xor(ci, m, 32);
        if (ov > cv || (ov == cv && oi < ci)) { cv = ov; ci = oi; }
    }
    if (pr == 0) {
        out_max[p] = cv;
        slab[p] = (__float_as_uint(s) & ~31u) | (unsigned)ci;  // sq trunc 2^-18 rel, harmless
    }
}

// 16 waves/block. Wave wv owns groups g ≡ wv (mod 16): pair p covers groups
// (wv + 32p, wv + 32p + 16); 16 pairs = 32 groups = 512 j-rows per wave.
// 8 outer iterations x (2 pairs -> 16 candidates -> sort63 + merge48).
__global__ __launch_bounds__(1024, 8) void main_kernel(
    const char* __restrict__ enc1, const char* __restrict__ enc2,
    const unsigned int* __restrict__ slab, const int* __restrict__ kptr,
    float* __restrict__ out_ent, float* __restrict__ out_glob)
{
    __shared__ unsigned wl[WAVES * 16 * 17];   // 17408 B epilogue merge area
    __shared__ int cnt[32];
    // ~17.5 KB LDS; occupancy = 2 blocks/CU x 16 waves = 32 waves/CU (grid 512 exactly co-resident)

    const int tid  = threadIdx.x, bid = blockIdx.x;
    const int wv   = tid >> 6, lane = tid & 63;
    const int quad = (tid >> 4) & 3, c15 = tid & 15;
    const int rowbase = bid * RT;

    // i-fragments: all waves read the same 4 KB group (L1 broadcast), hoisted
    short8 bh[2], bl[2];
    {
        const char* ib = enc1 + (size_t)bid * 4096 + lane * 16;
        bh[0] = *(const short8*)(ib);
        bh[1] = *(const short8*)(ib + 1024);
        bl[0] = *(const short8*)(ib + 2048);
        bl[1] = *(const short8*)(ib + 3072);
    }
    const float sqi = __uint_as_float(slab[rowbase + c15] & ~31u);

    unsigned ls[KCAP];   // per-thread sorted-ascending top-16: bits(d2)&~31 | label
    #pragma unroll
    for (int q = 0; q < KCAP; ++q) ls[q] = 0xFFFFFFFFu;
    unsigned cand[16];

    // per-lane base + uniform wrapping byte offset into enc2 (pair stride 128 KB)
    const char* jb = enc2 + lane * 16;
    unsigned jo = (unsigned)wv * 4096u;              // tile A of pair 0
    const unsigned* sp = slab + wv * 16 + quad * 4;  // pair stride +512 u32; tile B at +256

    // ---- software pipeline: ping-pong pair buffers, prefetch one pair ahead ----
    short8 Ah0 = *(const short8*)(jb + jo);
    short8 Ah1 = *(const short8*)(jb + jo + 1024);
    short8 Al0 = *(const short8*)(jb + jo + 2048);
    short8 Al1 = *(const short8*)(jb + jo + 3072);
    short8 Ch0 = *(const short8*)(jb + jo + 65536);
    short8 Ch1 = *(const short8*)(jb + jo + 66560);
    short8 Cl0 = *(const short8*)(jb + jo + 67584);
    short8 Cl1 = *(const short8*)(jb + jo + 68608);
    uint4  Asva = *(const uint4*)(sp);
    uint4  Asvb = *(const uint4*)(sp + 256);

    for (int t = 0; t < 8; ++t) {
        // prefetch pair 2t+1 into B buffers
        jo = (jo + 131072u) & JMASK; sp += 512;
        short8 Bh0 = *(const short8*)(jb + jo);
        short8 Bh1 = *(const short8*)(jb + jo + 1024);
        short8 Bl0 = *(const short8*)(jb + jo + 2048);
        short8 Bl1 = *(const short8*)(jb + jo + 3072);
        short8 Dh0 = *(const short8*)(jb + jo + 65536);
        short8 Dh1 = *(const short8*)(jb + jo + 66560);
        short8 Dl0 = *(const short8*)(jb + jo + 67584);
        short8 Dl1 = *(const short8*)(jb + jo + 68608);
        uint4  Bsva = *(const uint4*)(sp);
        uint4  Bsvb = *(const uint4*)(sp + 256);
        // compute pair 2t (A buffers)
        compute_pair(Ah0, Ah1, Al0, Al1, Ch0, Ch1, Cl0, Cl1, Asva, Asvb,
                     bh, bl, sqi, cand, 0);
        // prefetch pair 2t+2 into A buffers (last iter wraps via JMASK, unused)
        jo = (jo + 131072u) & JMASK; sp += 512;
        Ah0 = *(const short8*)(jb + jo);
        Ah1 = *(const short8*)(jb + jo + 1024);
        Al0 = *(const short8*)(jb + jo + 2048);
        Al1 = *(const short8*)(jb + jo + 3072);
        Ch0 = *(const short8*)(jb + jo + 65536);
        Ch1 = *(const short8*)(jb + jo + 66560);
        Cl0 = *(const short8*)(jb + jo + 67584);
        Cl1 = *(const short8*)(jb + jo + 68608);
        Asva = *(const uint4*)(sp);
        Asvb = *(const uint4*)(sp + 256);
        // compute pair 2t+1 (B buffers)
        compute_pair(Bh0, Bh1, Bl0, Bl1, Dh0, Dh1, Dl0, Dl1, Bsva, Bsvb,
                     bh, bl, sqi, cand, 8);
        // branchless selection on the 16-candidate batch (overlaps A-prefetch flight)
        oesort16(cand);
        bmerge16(ls, cand);
    }

    // ---- block 0: global cluster entropy from slab labels (block-uniform branch) ----
    if (bid == 0) {
        if (tid < 32) cnt[tid] = 0;
        __syncthreads();
        for (int i = tid; i < Bsz; i += 1024) atomicAdd(&cnt[slab[i] & 31u], 1);
        __syncthreads();
        if (tid == 0) {
            float gent = 0.f, npop = 0.f;
            for (int i = 0; i < NC; ++i) {
                int g = cnt[i];
                if (g > 0) {
                    npop += 1.f;
                    float gb = (float)g / (float)Bsz;
                    gent -= gb * logf(gb + EPSf);
                }
            }
            out_glob[0] = gent;
            out_glob[1] = npop;
        }
        __syncthreads();
    }

    // ---- epilogue: merge 4 quads (shfl), then 16 waves (LDS), per i-row ----
    bmerge16_shfl(ls, 16);   // quad ^ 1
    bmerge16_shfl(ls, 32);   // quad ^ 2 -> wave-level sorted top-16 in all quads
    if (quad == 0) {
        #pragma unroll
        for (int q = 0; q < KCAP; ++q) wl[(wv * 16 + c15) * 17 + q] = ls[q];
    }
    __syncthreads();
    if (wv == 0) {   // 64 threads: 16 rows x 4 subs, merge 16 wave-lists -> entropy
        const int row = tid >> 2, sub = tid & 3;
        unsigned A[16], Bv[16];
        #pragma unroll
        for (int i = 0; i < 16; ++i) A[i]  = wl[((4 * sub)     * 16 + row) * 17 + i];
        #pragma unroll
        for (int i = 0; i < 16; ++i) Bv[i] = wl[((4 * sub + 1) * 16 + row) * 17 + i];
        bmerge16(A, Bv);
        #pragma unroll
        for (int i = 0; i < 16; ++i) Bv[i] = wl[((4 * sub + 2) * 16 + row) * 17 + i];
        bmerge16(A, Bv);
        #pragma unroll
        for (int i = 0; i < 16; ++i) Bv[i] = wl[((4 * sub + 3) * 16 + row) * 17 + i];
        bmerge16(A, Bv);
        bmerge16_shfl(A, 1);   // sub ^ 1
        bmerge16_shfl(A, 2);   // sub ^ 2 -> row's global sorted top-16 in all subs

        int kk = kptr[0];
        if (kk > Bsz / 4) kk = Bsz / 4;
        if (kk > KCAP - 1) kk = KCAP - 1;

        unsigned kth = A[15];
        #pragma unroll
        for (int q = 0; q < 16; ++q) if (q == kk) kth = A[q];
        int nn = 0;
        #pragma unroll
        for (int t = 0; t < 15; ++t) nn += (t < kk && A[t] < kth) ? 1 : 0;  // strict <, sorted prefix

        float inv = 1.f / (float)((nn > 0) ? nn : 1);
        float part = 0.f;
        #pragma unroll
        for (int a4 = 0; a4 < 4; ++a4) {
            int a = sub + 4 * a4;
            if (a < nn) {
                int la = (int)(A[a] & 31u);
                int c = 0;
                #pragma unroll
                for (int b = 0; b < 15; ++b) c += (b < nn && (int)(A[b] & 31u) == la) ? 1 : 0;
                part -= inv * logf((float)c * inv + EPSf);
            }
        }
        part += __shfl_xor(part, 1);
        part += __shfl_xor(part, 2);
        if (sub == 0) out_ent[rowbase + row] = part;
    }
}

extern "C" void kernel_launch(void* const* d_in, const int* in_sizes, int n_in,
                              void* d_out, int out_size, void* d_ws, size_t ws_size,
                              hipStream_t stream)
{
    const float* enc  = (const float*)d_in[0];
    const float* cat  = (const float*)d_in[1];
    const int*   kptr = (const int*)d_in[2];
    float* out = (float*)d_out;

    unsigned int* slab = (unsigned int*)d_ws;
    char*         enc1 = (char*)d_ws + 32768;
    char*         enc2 = (char*)d_ws + 2129920;

    float* out_enc  = out;
    float* out_ent  = out + Bsz * Dd;                 // 524288
    float* out_glob = out + Bsz * Dd + Bsz;           // 532480 (entropy, n_populated)
    float* out_max  = out + Bsz * Dd + Bsz + 2;       // 532482

    pre_kernel<<<1024, 256, 0, stream>>>(enc, cat, slab, enc1, enc2, out_max, out_enc);
    main_kernel<<<Bsz / RT, 1024, 0, stream>>>(enc1, enc2, slab, kptr, out_ent, out_glob);
}